// Round 1
// baseline (1734.908 us; speedup 1.0000x reference)
//
#include <hip/hip_runtime.h>

#define NN 100000
#define EE 1600000
#define BBATCH 256
#define FIN 1280
#define HH 128

using short8 = __attribute__((ext_vector_type(8))) short;
using f32x4  = __attribute__((ext_vector_type(4))) float;

static __device__ __forceinline__ unsigned short f2bf(float f) {
  union { float f; unsigned int u; } un; un.f = f;
  unsigned int u = un.u;
  return (unsigned short)((u + 0x7fffu + ((u >> 16) & 1u)) >> 16);  // RTNE
}

// ---------------- degree histogram over edge dst ----------------
__global__ void k_hist(const int* __restrict__ dst, int* __restrict__ cnt, int e_total) {
  int e = blockIdx.x * blockDim.x + threadIdx.x;
  if (e < e_total) atomicAdd(&cnt[dst[e]], 1);
}

// ------- exclusive scan cnt -> rowptr; dinv = rsqrt(cnt+1) (self-loop) -------
__global__ __launch_bounds__(1024) void k_scan(const int* __restrict__ cnt,
                                               int* __restrict__ rowptr,
                                               float* __restrict__ dinv, int n) {
  const int tid = threadIdx.x;
  const int lane = tid & 63, wid = tid >> 6;
  __shared__ int wsum[16];
  int base = 0;
  const int PER = 8;
  const int CHUNK = 1024 * PER;
  for (int start = 0; start < n; start += CHUNK) {
    int idx0 = start + tid * PER;
    int v[PER]; int local = 0;
#pragma unroll
    for (int k = 0; k < PER; ++k) {
      int i = idx0 + k;
      v[k] = (i < n) ? cnt[i] : 0;
      local += v[k];
    }
    int sc = local;
#pragma unroll
    for (int off = 1; off < 64; off <<= 1) {
      int t = __shfl_up(sc, off, 64);
      if (lane >= off) sc += t;
    }
    if (lane == 63) wsum[wid] = sc;
    __syncthreads();
    if (wid == 0) {
      int ws_ = (lane < 16) ? wsum[lane] : 0;
#pragma unroll
      for (int off = 1; off < 16; off <<= 1) {
        int t = __shfl_up(ws_, off, 64);
        if (lane >= off) ws_ += t;
      }
      if (lane < 16) wsum[lane] = ws_;
    }
    __syncthreads();
    int wave_excl = (wid == 0) ? 0 : wsum[wid - 1];
    int excl = base + wave_excl + (sc - local);
#pragma unroll
    for (int k = 0; k < PER; ++k) {
      int i = idx0 + k;
      if (i < n) { rowptr[i] = excl; dinv[i] = rsqrtf((float)(v[k] + 1)); }
      excl += v[k];
    }
    int total = wsum[15];
    __syncthreads();
    base += total;
  }
  if (tid == 0) rowptr[n] = base;
}

// ---------------- CSR fill: edges bucketed by dst ----------------
__global__ void k_fill(const int* __restrict__ src, const int* __restrict__ dst,
                       const int* __restrict__ rowptr, int* __restrict__ fillp,
                       int* __restrict__ esrc, float* __restrict__ enorm,
                       const float* __restrict__ dinv, int e_total) {
  int e = blockIdx.x * blockDim.x + threadIdx.x;
  if (e >= e_total) return;
  int s = src[e], d = dst[e];
  int p = rowptr[d] + atomicAdd(&fillp[d], 1);
  esrc[p] = s;
  enorm[p] = dinv[s] * dinv[d];
}

// ---------------- W [K][C] fp32 -> Wt [C][K] bf16 ----------------
__global__ void k_transW(const float* __restrict__ W, unsigned short* __restrict__ Wt,
                         int K, int Ccols) {
  int idx = blockIdx.x * blockDim.x + threadIdx.x;
  if (idx >= K * Ccols) return;
  int nrow = idx / K, k = idx - nrow * K;
  Wt[idx] = f2bf(W[(size_t)k * Ccols + nrow]);
}

// ---------------- C[M][128] = A[M][K] (fp32) x Bt[128][K] (bf16) ----------------
// 128-row block, 256 thr = 4 waves; wave computes 2 row-tiles x 8 col-tiles (16x16x32 MFMA)
__global__ __launch_bounds__(256) void k_gemm(const float* __restrict__ A,
                                              const unsigned short* __restrict__ Bt,
                                              float* __restrict__ C,
                                              int M, int K) {
  __shared__ unsigned short As[128][40];  // +8 pad (16B) keeps ds_read_b128 clean
  __shared__ unsigned short Bs[128][40];
  const int tid = threadIdx.x;
  const int lane = tid & 63, wid = tid >> 6;
  const int row0 = blockIdx.x * 128;
  const int ar = tid >> 1;
  const int ah = (tid & 1) * 16;
  const int q = lane >> 4, r16 = lane & 15;

  f32x4 acc[2][8];
#pragma unroll
  for (int i = 0; i < 2; ++i)
#pragma unroll
    for (int j = 0; j < 8; ++j) { f32x4 z = {0.f, 0.f, 0.f, 0.f}; acc[i][j] = z; }

  const int grow = row0 + ar;
  const bool avalid = grow < M;
  const float* aprow = A + (size_t)grow * K + ah;
  const unsigned short* bprow = Bt + (size_t)ar * K + ah;

  for (int k0 = 0; k0 < K; k0 += 32) {
#pragma unroll
    for (int i = 0; i < 4; ++i) {
      float4 v = avalid ? *(const float4*)(aprow + k0 + i * 4) : make_float4(0.f, 0.f, 0.f, 0.f);
      ushort4 b;
      b.x = f2bf(v.x); b.y = f2bf(v.y); b.z = f2bf(v.z); b.w = f2bf(v.w);
      *(ushort4*)&As[ar][ah + i * 4] = b;
    }
#pragma unroll
    for (int i = 0; i < 2; ++i) {
      uint4 vv = *(const uint4*)(bprow + k0 + i * 8);
      *(uint4*)&Bs[ar][ah + i * 8] = vv;
    }
    __syncthreads();
    short8 afr[2], bfr[8];
#pragma unroll
    for (int i = 0; i < 2; ++i) {
      int rt = wid * 2 + i;
      afr[i] = *(const short8*)&As[rt * 16 + r16][q * 8];
    }
#pragma unroll
    for (int ct = 0; ct < 8; ++ct)
      bfr[ct] = *(const short8*)&Bs[ct * 16 + r16][q * 8];
#pragma unroll
    for (int i = 0; i < 2; ++i)
#pragma unroll
      for (int ct = 0; ct < 8; ++ct)
        acc[i][ct] = __builtin_amdgcn_mfma_f32_16x16x32_bf16(afr[i], bfr[ct], acc[i][ct], 0, 0, 0);
    __syncthreads();
  }

#pragma unroll
  for (int i = 0; i < 2; ++i) {
    int rt = wid * 2 + i;
#pragma unroll
    for (int rr = 0; rr < 4; ++rr) {
      int gr = row0 + rt * 16 + q * 4 + rr;
      if (gr < M) {
        float* cp = C + (size_t)gr * 128 + r16;
#pragma unroll
        for (int ct = 0; ct < 8; ++ct) cp[ct * 16] = acc[i][ct][rr];
      }
    }
  }
}

// ------- per-dst gather (CSR) + self-loop + bias + (ReLU) + BN, fused -------
// one wave per dst row; lane owns channels 2*lane, 2*lane+1
__global__ __launch_bounds__(256) void k_gather(
    const float* __restrict__ h, const int* __restrict__ rowptr,
    const int* __restrict__ esrc, const float* __restrict__ enorm,
    const float* __restrict__ dinv, const float* __restrict__ bias,
    const float* __restrict__ gg, const float* __restrict__ bb,
    const float* __restrict__ mm, const float* __restrict__ vv,
    float* __restrict__ out, int n, int relu) {
  int d = blockIdx.x * 4 + (threadIdx.x >> 6);
  if (d >= n) return;
  int lane = threadIdx.x & 63;
  const float2* hp = (const float2*)h;
  float wd = dinv[d];
  float2 hv = hp[(size_t)d * 64 + lane];
  float acx = wd * wd * hv.x, acy = wd * wd * hv.y;
  int j0 = rowptr[d], j1 = rowptr[d + 1];
  for (int j = j0; j < j1; ++j) {
    int s = esrc[j];
    float w = enorm[j];
    float2 x = hp[(size_t)s * 64 + lane];
    acx = fmaf(w, x.x, acx);
    acy = fmaf(w, x.y, acy);
  }
  int c = lane * 2;
  float vx = acx + bias[c], vy = acy + bias[c + 1];
  if (relu) { vx = fmaxf(vx, 0.f); vy = fmaxf(vy, 0.f); }
  float sx = gg[c] * rsqrtf(vv[c] + 1e-5f);
  float sy = gg[c + 1] * rsqrtf(vv[c + 1] + 1e-5f);
  float2 o;
  o.x = (vx - mm[c]) * sx + bb[c];
  o.y = (vy - mm[c + 1]) * sy + bb[c + 1];
  ((float2*)out)[(size_t)d * 64 + lane] = o;
}

// ---------------- mean-pool per graph (batch sorted -> binary search) ----------------
__global__ __launch_bounds__(256) void k_pool(const float* __restrict__ x,
                                              const int* __restrict__ batch,
                                              float* __restrict__ pooled, int n) {
  int b = blockIdx.x;
  int lo = 0, hi = n;
  while (lo < hi) { int mid = (lo + hi) >> 1; if (batch[mid] < b) lo = mid + 1; else hi = mid; }
  int start = lo;
  hi = n;
  while (lo < hi) { int mid = (lo + hi) >> 1; if (batch[mid] < b + 1) lo = mid + 1; else hi = mid; }
  int end = lo;
  int lane = threadIdx.x & 63, wid = threadIdx.x >> 6;
  const float2* xp = (const float2*)x;
  float ax = 0.f, ay = 0.f;
  for (int i = start + wid; i < end; i += 4) {
    float2 t = xp[(size_t)i * 64 + lane];
    ax += t.x; ay += t.y;
  }
  __shared__ float px[4][64], py[4][64];
  px[wid][lane] = ax; py[wid][lane] = ay;
  __syncthreads();
  if (wid == 0) {
    float sx = px[0][lane] + px[1][lane] + px[2][lane] + px[3][lane];
    float sy = py[0][lane] + py[1][lane] + py[2][lane] + py[3][lane];
    float inv = 1.0f / fmaxf((float)(end - start), 1.0f);
    float2 o; o.x = sx * inv; o.y = sy * inv;
    ((float2*)pooled)[b * 64 + lane] = o;
  }
}

// ---------------- z = pooled + x_seq@fcW + fcb; two sigmoid heads ----------------
__global__ __launch_bounds__(256) void k_head(
    const float* __restrict__ pooled, const float* __restrict__ x_seq,
    const float* __restrict__ fcW, const float* __restrict__ fcb,
    const float* __restrict__ l0W, const float* __restrict__ l0b,
    const float* __restrict__ l1W, const float* __restrict__ l1b,
    float* __restrict__ out) {
  int b = blockIdx.x;
  int tid = threadIdx.x;
  __shared__ float xs[FIN];
  __shared__ float z[HH];
  for (int i = tid; i < FIN; i += 256) xs[i] = x_seq[(size_t)b * FIN + i];
  __syncthreads();
  if (tid < HH) {
    float acc = fcb[tid];
    for (int k = 0; k < FIN; ++k) acc = fmaf(xs[k], fcW[(size_t)k * HH + tid], acc);
    z[tid] = pooled[b * HH + tid] + acc;
  }
  __syncthreads();
  for (int o = tid; o < 365; o += 256) {
    if (o < 183) {
      float a = l0b[o];
      for (int k = 0; k < HH; ++k) a = fmaf(z[k], l0W[k * 183 + o], a);
      out[(size_t)b * 547 + o] = 1.f / (1.f + expf(-a));
    } else {
      int oo = o - 183;
      float a = l1b[oo];
      for (int k = 0; k < HH; ++k) a = fmaf(z[k], l1W[k * 182 + oo], a);
      float sv = 1.f / (1.f + expf(-a));
      out[(size_t)b * 547 + 183 + oo] = sv;
      out[(size_t)b * 547 + 365 + oo] = sv;
    }
  }
}

extern "C" void kernel_launch(void* const* d_in, const int* in_sizes, int n_in,
                              void* d_out, int out_size, void* d_ws, size_t ws_size,
                              hipStream_t stream) {
  const float* x_res = (const float*)d_in[0];
  const int*   eidx  = (const int*)d_in[1];
  const int*   batch = (const int*)d_in[2];
  const float* x_seq = (const float*)d_in[3];
  const float* W1 = (const float*)d_in[4];  const float* b1 = (const float*)d_in[5];
  const float* W2 = (const float*)d_in[6];  const float* b2 = (const float*)d_in[7];
  const float* W3 = (const float*)d_in[8];  const float* b3 = (const float*)d_in[9];
  const float* g1 = (const float*)d_in[10]; const float* be1 = (const float*)d_in[11];
  const float* m1 = (const float*)d_in[12]; const float* v1 = (const float*)d_in[13];
  const float* g2 = (const float*)d_in[14]; const float* be2 = (const float*)d_in[15];
  const float* m2 = (const float*)d_in[16]; const float* v2 = (const float*)d_in[17];
  const float* g3 = (const float*)d_in[18]; const float* be3 = (const float*)d_in[19];
  const float* m3 = (const float*)d_in[20]; const float* v3 = (const float*)d_in[21];
  const float* fcW = (const float*)d_in[22]; const float* fcb = (const float*)d_in[23];
  const float* l0W = (const float*)d_in[24]; const float* l0b = (const float*)d_in[25];
  const float* l1W = (const float*)d_in[26]; const float* l1b = (const float*)d_in[27];

  char* ws = (char*)d_ws;
  size_t off = 0;
  auto alloc = [&](size_t bytes) -> void* {
    void* p = ws + off;
    off += (bytes + 255) & ~(size_t)255;
    return p;
  };
  float* bufA = (float*)alloc((size_t)NN * HH * 4);
  float* bufB = (float*)alloc((size_t)NN * HH * 4);
  int* cnt    = (int*)alloc((size_t)NN * 4);
  int* rowptr = (int*)alloc(((size_t)NN + 1) * 4);
  int* fillp  = (int*)alloc((size_t)NN * 4);
  float* dinv = (float*)alloc((size_t)NN * 4);
  int* esrc   = (int*)alloc((size_t)EE * 4);
  float* enorm = (float*)alloc((size_t)EE * 4);
  unsigned short* W1t = (unsigned short*)alloc((size_t)HH * FIN * 2);
  unsigned short* W2t = (unsigned short*)alloc((size_t)HH * HH * 2);
  unsigned short* W3t = (unsigned short*)alloc((size_t)HH * HH * 2);
  float* pooled = (float*)alloc((size_t)BBATCH * HH * 4);

  const int* esrc_in = eidx;
  const int* edst_in = eidx + EE;

  hipMemsetAsync(cnt, 0, (size_t)NN * 4, stream);
  hipMemsetAsync(fillp, 0, (size_t)NN * 4, stream);

  k_hist<<<(EE + 255) / 256, 256, 0, stream>>>(edst_in, cnt, EE);
  k_scan<<<1, 1024, 0, stream>>>(cnt, rowptr, dinv, NN);
  k_fill<<<(EE + 255) / 256, 256, 0, stream>>>(esrc_in, edst_in, rowptr, fillp, esrc, enorm, dinv, EE);
  k_transW<<<(FIN * HH + 255) / 256, 256, 0, stream>>>(W1, W1t, FIN, HH);
  k_transW<<<(HH * HH + 255) / 256, 256, 0, stream>>>(W2, W2t, HH, HH);
  k_transW<<<(HH * HH + 255) / 256, 256, 0, stream>>>(W3, W3t, HH, HH);

  const int gemm_grid = (NN + 127) / 128;
  const int gat_grid  = (NN + 3) / 4;
  // layer 1
  k_gemm<<<gemm_grid, 256, 0, stream>>>(x_res, W1t, bufA, NN, FIN);
  k_gather<<<gat_grid, 256, 0, stream>>>(bufA, rowptr, esrc, enorm, dinv, b1, g1, be1, m1, v1, bufB, NN, 1);
  // layer 2
  k_gemm<<<gemm_grid, 256, 0, stream>>>(bufB, W2t, bufA, NN, HH);
  k_gather<<<gat_grid, 256, 0, stream>>>(bufA, rowptr, esrc, enorm, dinv, b2, g2, be2, m2, v2, bufB, NN, 1);
  // layer 3 (no relu)
  k_gemm<<<gemm_grid, 256, 0, stream>>>(bufB, W3t, bufA, NN, HH);
  k_gather<<<gat_grid, 256, 0, stream>>>(bufA, rowptr, esrc, enorm, dinv, b3, g3, be3, m3, v3, bufB, NN, 0);
  // pool + heads
  k_pool<<<BBATCH, 256, 0, stream>>>(bufB, batch, pooled, NN);
  k_head<<<BBATCH, 256, 0, stream>>>(pooled, x_seq, fcW, fcb, l0W, l0b, l1W, l1b, (float*)d_out);
}

// Round 2
// 1532.614 us; speedup vs baseline: 1.1320x; 1.1320x over previous
//
#include <hip/hip_runtime.h>

#define NN 100000
#define EE 1600000
#define BBATCH 256
#define FIN 1280
#define HH 128

using short8 = __attribute__((ext_vector_type(8))) short;
using f32x4  = __attribute__((ext_vector_type(4))) float;

static __device__ __forceinline__ unsigned short f2bf(float f) {
  union { float f; unsigned int u; } un; un.f = f;
  unsigned int u = un.u;
  return (unsigned short)((u + 0x7fffu + ((u >> 16) & 1u)) >> 16);  // RTNE
}
static __device__ __forceinline__ float bflo(unsigned int u) {
  union { unsigned int u; float f; } c; c.u = u << 16; return c.f;
}
static __device__ __forceinline__ float bfhi(unsigned int u) {
  union { unsigned int u; float f; } c; c.u = u & 0xffff0000u; return c.f;
}

// ---------------- degree histogram over edge dst ----------------
__global__ void k_hist(const int* __restrict__ dst, int* __restrict__ cnt, int e_total) {
  int e = blockIdx.x * blockDim.x + threadIdx.x;
  if (e < e_total) atomicAdd(&cnt[dst[e]], 1);
}

// ------- exclusive scan cnt -> rowptr; dinv = rsqrt(cnt+1) (self-loop) -------
__global__ __launch_bounds__(1024) void k_scan(const int* __restrict__ cnt,
                                               int* __restrict__ rowptr,
                                               float* __restrict__ dinv, int n) {
  const int tid = threadIdx.x;
  const int lane = tid & 63, wid = tid >> 6;
  __shared__ int wsum[16];
  int base = 0;
  const int PER = 8;
  const int CHUNK = 1024 * PER;
  for (int start = 0; start < n; start += CHUNK) {
    int idx0 = start + tid * PER;
    int v[PER]; int local = 0;
#pragma unroll
    for (int k = 0; k < PER; ++k) {
      int i = idx0 + k;
      v[k] = (i < n) ? cnt[i] : 0;
      local += v[k];
    }
    int sc = local;
#pragma unroll
    for (int off = 1; off < 64; off <<= 1) {
      int t = __shfl_up(sc, off, 64);
      if (lane >= off) sc += t;
    }
    if (lane == 63) wsum[wid] = sc;
    __syncthreads();
    if (wid == 0) {
      int ws_ = (lane < 16) ? wsum[lane] : 0;
#pragma unroll
      for (int off = 1; off < 16; off <<= 1) {
        int t = __shfl_up(ws_, off, 64);
        if (lane >= off) ws_ += t;
      }
      if (lane < 16) wsum[lane] = ws_;
    }
    __syncthreads();
    int wave_excl = (wid == 0) ? 0 : wsum[wid - 1];
    int excl = base + wave_excl + (sc - local);
#pragma unroll
    for (int k = 0; k < PER; ++k) {
      int i = idx0 + k;
      if (i < n) { rowptr[i] = excl; dinv[i] = rsqrtf((float)(v[k] + 1)); }
      excl += v[k];
    }
    int total = wsum[15];
    __syncthreads();
    base += total;
  }
  if (tid == 0) rowptr[n] = base;
}

// -------- CSR fill: edges bucketed by dst; packed (src, norm) --------
__global__ void k_fill(const int* __restrict__ src, const int* __restrict__ dst,
                       const int* __restrict__ rowptr, int* __restrict__ fillp,
                       int2* __restrict__ epk, const float* __restrict__ dinv,
                       int e_total) {
  int e = blockIdx.x * blockDim.x + threadIdx.x;
  if (e >= e_total) return;
  int s = src[e], d = dst[e];
  int p = rowptr[d] + atomicAdd(&fillp[d], 1);
  epk[p] = make_int2(s, __float_as_int(dinv[s] * dinv[d]));
}

// ---------------- W [K][C] fp32 -> Wt [C][K] bf16 ----------------
__global__ void k_transW(const float* __restrict__ W, unsigned short* __restrict__ Wt,
                         int K, int Ccols) {
  int idx = blockIdx.x * blockDim.x + threadIdx.x;
  if (idx >= K * Ccols) return;
  int nrow = idx / K, k = idx - nrow * K;
  Wt[idx] = f2bf(W[(size_t)k * Ccols + nrow]);
}

// ------- C[M][128] (bf16) = A[M][K] (fp32 or bf16) x Bt[128][K] (bf16) -------
// 128-row block, 256 thr = 4 waves; wave computes 2 row-tiles x 8 col-tiles (16x16x32)
template <int ABF>
__global__ __launch_bounds__(256) void k_gemm(const void* __restrict__ Av,
                                              const unsigned short* __restrict__ Bt,
                                              unsigned short* __restrict__ C,
                                              int M, int K) {
  __shared__ unsigned short As[128][40];  // +8 pad (16B) keeps ds_read_b128 clean
  __shared__ unsigned short Bs[128][40];
  const int tid = threadIdx.x;
  const int lane = tid & 63, wid = tid >> 6;
  const int row0 = blockIdx.x * 128;
  const int ar = tid >> 1;
  const int ah = (tid & 1) * 16;
  const int q = lane >> 4, r16 = lane & 15;

  f32x4 acc[2][8];
#pragma unroll
  for (int i = 0; i < 2; ++i)
#pragma unroll
    for (int j = 0; j < 8; ++j) { f32x4 z = {0.f, 0.f, 0.f, 0.f}; acc[i][j] = z; }

  const int grow = row0 + ar;
  const bool avalid = grow < M;
  const float* aprow = (const float*)Av + (size_t)grow * K + ah;
  const unsigned short* aprow16 = (const unsigned short*)Av + (size_t)grow * K + ah;
  const unsigned short* bprow = Bt + (size_t)ar * K + ah;

  for (int k0 = 0; k0 < K; k0 += 32) {
    if (ABF) {
#pragma unroll
      for (int i = 0; i < 2; ++i) {
        uint4 vv;
        if (avalid) vv = *(const uint4*)(aprow16 + k0 + i * 8);
        else { vv.x = 0; vv.y = 0; vv.z = 0; vv.w = 0; }
        *(uint4*)&As[ar][ah + i * 8] = vv;
      }
    } else {
#pragma unroll
      for (int i = 0; i < 4; ++i) {
        float4 v = avalid ? *(const float4*)(aprow + k0 + i * 4) : make_float4(0.f, 0.f, 0.f, 0.f);
        ushort4 b;
        b.x = f2bf(v.x); b.y = f2bf(v.y); b.z = f2bf(v.z); b.w = f2bf(v.w);
        *(ushort4*)&As[ar][ah + i * 4] = b;
      }
    }
#pragma unroll
    for (int i = 0; i < 2; ++i) {
      uint4 vv = *(const uint4*)(bprow + k0 + i * 8);
      *(uint4*)&Bs[ar][ah + i * 8] = vv;
    }
    __syncthreads();
    short8 afr[2], bfr[8];
#pragma unroll
    for (int i = 0; i < 2; ++i) {
      int rt = wid * 2 + i;
      afr[i] = *(const short8*)&As[rt * 16 + r16][q * 8];
    }
#pragma unroll
    for (int ct = 0; ct < 8; ++ct)
      bfr[ct] = *(const short8*)&Bs[ct * 16 + r16][q * 8];
#pragma unroll
    for (int i = 0; i < 2; ++i)
#pragma unroll
      for (int ct = 0; ct < 8; ++ct)
        acc[i][ct] = __builtin_amdgcn_mfma_f32_16x16x32_bf16(afr[i], bfr[ct], acc[i][ct], 0, 0, 0);
    __syncthreads();
  }

#pragma unroll
  for (int i = 0; i < 2; ++i) {
    int rt = wid * 2 + i;
#pragma unroll
    for (int rr = 0; rr < 4; ++rr) {
      int gr = row0 + rt * 16 + q * 4 + rr;
      if (gr < M) {
        unsigned short* cp = C + (size_t)gr * 128 + r16;
#pragma unroll
        for (int ct = 0; ct < 8; ++ct) cp[ct * 16] = f2bf(acc[i][ct][rr]);
      }
    }
  }
}

// ------- per-dst gather (CSR, bf16 h) + self-loop + bias + (ReLU) + BN -------
// one wave per dst row; lane owns channels 2*lane, 2*lane+1
// edges read in coalesced 64-chunks, broadcast via shuffle -> many row loads in flight
__global__ __launch_bounds__(256) void k_gather(
    const unsigned short* __restrict__ h, const int* __restrict__ rowptr,
    const int2* __restrict__ epk, const float* __restrict__ dinv,
    const float* __restrict__ bias,
    const float* __restrict__ gg, const float* __restrict__ bb,
    const float* __restrict__ mm, const float* __restrict__ vv,
    unsigned short* __restrict__ out, int n, int relu) {
  int d = blockIdx.x * 4 + (threadIdx.x >> 6);
  if (d >= n) return;
  int lane = threadIdx.x & 63;
  const unsigned int* hp = (const unsigned int*)h;
  float wd = dinv[d];
  unsigned int hv = hp[(size_t)d * 64 + lane];
  float acx = wd * wd * bflo(hv), acy = wd * wd * bfhi(hv);
  int j0 = rowptr[d], j1 = rowptr[d + 1];
  for (int base = j0; base < j1; base += 64) {
    int idx = base + lane;
    int2 e = epk[min(idx, j1 - 1)];
    int cntk = min(64, j1 - base);
    for (int k = 0; k < cntk; ++k) {
      int s = __shfl(e.x, k, 64);
      float w = __int_as_float(__shfl(e.y, k, 64));
      unsigned int x = hp[(size_t)s * 64 + lane];
      acx = fmaf(w, bflo(x), acx);
      acy = fmaf(w, bfhi(x), acy);
    }
  }
  float2 bia = ((const float2*)bias)[lane];
  float2 gv = ((const float2*)gg)[lane];
  float2 bv = ((const float2*)bb)[lane];
  float2 mv = ((const float2*)mm)[lane];
  float2 vva = ((const float2*)vv)[lane];
  float vx = acx + bia.x, vy = acy + bia.y;
  if (relu) { vx = fmaxf(vx, 0.f); vy = fmaxf(vy, 0.f); }
  float ox = (vx - mv.x) * (gv.x * rsqrtf(vva.x + 1e-5f)) + bv.x;
  float oy = (vy - mv.y) * (gv.y * rsqrtf(vva.y + 1e-5f)) + bv.y;
  unsigned int packed = (unsigned int)f2bf(ox) | ((unsigned int)f2bf(oy) << 16);
  ((unsigned int*)out)[(size_t)d * 64 + lane] = packed;
}

// ------------ mean-pool per graph (batch sorted -> binary search), bf16 in ------------
__global__ __launch_bounds__(256) void k_pool(const unsigned short* __restrict__ x,
                                              const int* __restrict__ batch,
                                              float* __restrict__ pooled, int n) {
  int b = blockIdx.x;
  int lo = 0, hi = n;
  while (lo < hi) { int mid = (lo + hi) >> 1; if (batch[mid] < b) lo = mid + 1; else hi = mid; }
  int start = lo;
  hi = n;
  while (lo < hi) { int mid = (lo + hi) >> 1; if (batch[mid] < b + 1) lo = mid + 1; else hi = mid; }
  int end = lo;
  int lane = threadIdx.x & 63, wid = threadIdx.x >> 6;
  const unsigned int* xp = (const unsigned int*)x;
  float ax = 0.f, ay = 0.f;
  for (int i = start + wid; i < end; i += 4) {
    unsigned int t = xp[(size_t)i * 64 + lane];
    ax += bflo(t); ay += bfhi(t);
  }
  __shared__ float px[4][64], py[4][64];
  px[wid][lane] = ax; py[wid][lane] = ay;
  __syncthreads();
  if (wid == 0) {
    float sx = px[0][lane] + px[1][lane] + px[2][lane] + px[3][lane];
    float sy = py[0][lane] + py[1][lane] + py[2][lane] + py[3][lane];
    float inv = 1.0f / fmaxf((float)(end - start), 1.0f);
    float2 o; o.x = sx * inv; o.y = sy * inv;
    ((float2*)pooled)[b * 64 + lane] = o;
  }
}

// ---------------- z = pooled + x_seq@fcW + fcb; two sigmoid heads ----------------
__global__ __launch_bounds__(256) void k_head(
    const float* __restrict__ pooled, const float* __restrict__ x_seq,
    const float* __restrict__ fcW, const float* __restrict__ fcb,
    const float* __restrict__ l0W, const float* __restrict__ l0b,
    const float* __restrict__ l1W, const float* __restrict__ l1b,
    float* __restrict__ out) {
  int b = blockIdx.x;
  int tid = threadIdx.x;
  __shared__ float xs[FIN];
  __shared__ float z[HH];
  for (int i = tid; i < FIN; i += 256) xs[i] = x_seq[(size_t)b * FIN + i];
  __syncthreads();
  if (tid < HH) {
    float acc = fcb[tid];
    for (int k = 0; k < FIN; ++k) acc = fmaf(xs[k], fcW[(size_t)k * HH + tid], acc);
    z[tid] = pooled[b * HH + tid] + acc;
  }
  __syncthreads();
  for (int o = tid; o < 365; o += 256) {
    if (o < 183) {
      float a = l0b[o];
      for (int k = 0; k < HH; ++k) a = fmaf(z[k], l0W[k * 183 + o], a);
      out[(size_t)b * 547 + o] = 1.f / (1.f + expf(-a));
    } else {
      int oo = o - 183;
      float a = l1b[oo];
      for (int k = 0; k < HH; ++k) a = fmaf(z[k], l1W[k * 182 + oo], a);
      float sv = 1.f / (1.f + expf(-a));
      out[(size_t)b * 547 + 183 + oo] = sv;
      out[(size_t)b * 547 + 365 + oo] = sv;
    }
  }
}

extern "C" void kernel_launch(void* const* d_in, const int* in_sizes, int n_in,
                              void* d_out, int out_size, void* d_ws, size_t ws_size,
                              hipStream_t stream) {
  const float* x_res = (const float*)d_in[0];
  const int*   eidx  = (const int*)d_in[1];
  const int*   batch = (const int*)d_in[2];
  const float* x_seq = (const float*)d_in[3];
  const float* W1 = (const float*)d_in[4];  const float* b1 = (const float*)d_in[5];
  const float* W2 = (const float*)d_in[6];  const float* b2 = (const float*)d_in[7];
  const float* W3 = (const float*)d_in[8];  const float* b3 = (const float*)d_in[9];
  const float* g1 = (const float*)d_in[10]; const float* be1 = (const float*)d_in[11];
  const float* m1 = (const float*)d_in[12]; const float* v1 = (const float*)d_in[13];
  const float* g2 = (const float*)d_in[14]; const float* be2 = (const float*)d_in[15];
  const float* m2 = (const float*)d_in[16]; const float* v2 = (const float*)d_in[17];
  const float* g3 = (const float*)d_in[18]; const float* be3 = (const float*)d_in[19];
  const float* m3 = (const float*)d_in[20]; const float* v3 = (const float*)d_in[21];
  const float* fcW = (const float*)d_in[22]; const float* fcb = (const float*)d_in[23];
  const float* l0W = (const float*)d_in[24]; const float* l0b = (const float*)d_in[25];
  const float* l1W = (const float*)d_in[26]; const float* l1b = (const float*)d_in[27];

  char* ws = (char*)d_ws;
  size_t off = 0;
  auto alloc = [&](size_t bytes) -> void* {
    void* p = ws + off;
    off += (bytes + 255) & ~(size_t)255;
    return p;
  };
  unsigned short* bufA = (unsigned short*)alloc((size_t)NN * HH * 2);
  unsigned short* bufB = (unsigned short*)alloc((size_t)NN * HH * 2);
  int* cnt    = (int*)alloc((size_t)NN * 4);
  int* rowptr = (int*)alloc(((size_t)NN + 1) * 4);
  int* fillp  = (int*)alloc((size_t)NN * 4);
  float* dinv = (float*)alloc((size_t)NN * 4);
  int2* epk   = (int2*)alloc((size_t)EE * 8);
  unsigned short* W1t = (unsigned short*)alloc((size_t)HH * FIN * 2);
  unsigned short* W2t = (unsigned short*)alloc((size_t)HH * HH * 2);
  unsigned short* W3t = (unsigned short*)alloc((size_t)HH * HH * 2);
  float* pooled = (float*)alloc((size_t)BBATCH * HH * 4);

  const int* esrc_in = eidx;
  const int* edst_in = eidx + EE;

  hipMemsetAsync(cnt, 0, (size_t)NN * 4, stream);
  hipMemsetAsync(fillp, 0, (size_t)NN * 4, stream);

  k_hist<<<(EE + 255) / 256, 256, 0, stream>>>(edst_in, cnt, EE);
  k_scan<<<1, 1024, 0, stream>>>(cnt, rowptr, dinv, NN);
  k_fill<<<(EE + 255) / 256, 256, 0, stream>>>(esrc_in, edst_in, rowptr, fillp, epk, dinv, EE);
  k_transW<<<(FIN * HH + 255) / 256, 256, 0, stream>>>(W1, W1t, FIN, HH);
  k_transW<<<(HH * HH + 255) / 256, 256, 0, stream>>>(W2, W2t, HH, HH);
  k_transW<<<(HH * HH + 255) / 256, 256, 0, stream>>>(W3, W3t, HH, HH);

  const int gemm_grid = (NN + 127) / 128;
  const int gat_grid  = (NN + 3) / 4;
  // layer 1 (A fp32)
  k_gemm<0><<<gemm_grid, 256, 0, stream>>>(x_res, W1t, bufA, NN, FIN);
  k_gather<<<gat_grid, 256, 0, stream>>>(bufA, rowptr, epk, dinv, b1, g1, be1, m1, v1, bufB, NN, 1);
  // layer 2 (A bf16)
  k_gemm<1><<<gemm_grid, 256, 0, stream>>>(bufB, W2t, bufA, NN, HH);
  k_gather<<<gat_grid, 256, 0, stream>>>(bufA, rowptr, epk, dinv, b2, g2, be2, m2, v2, bufB, NN, 1);
  // layer 3 (A bf16, no relu)
  k_gemm<1><<<gemm_grid, 256, 0, stream>>>(bufB, W3t, bufA, NN, HH);
  k_gather<<<gat_grid, 256, 0, stream>>>(bufA, rowptr, epk, dinv, b3, g3, be3, m3, v3, bufB, NN, 0);
  // pool + heads
  k_pool<<<BBATCH, 256, 0, stream>>>(bufB, batch, pooled, NN);
  k_head<<<BBATCH, 256, 0, stream>>>(pooled, x_seq, fcW, fcb, l0W, l0b, l1W, l1b, (float*)d_out);
}

// Round 3
// 1401.898 us; speedup vs baseline: 1.2375x; 1.0932x over previous
//
#include <hip/hip_runtime.h>

#define NN 100000
#define EE 1600000
#define BBATCH 256
#define FIN 1280
#define HH 128

using short8 = __attribute__((ext_vector_type(8))) short;
using f32x4  = __attribute__((ext_vector_type(4))) float;

static __device__ __forceinline__ unsigned short f2bf(float f) {
  union { float f; unsigned int u; } un; un.f = f;
  unsigned int u = un.u;
  return (unsigned short)((u + 0x7fffu + ((u >> 16) & 1u)) >> 16);  // RTNE
}
static __device__ __forceinline__ float bflo(unsigned int u) {
  union { unsigned int u; float f; } c; c.u = u << 16; return c.f;
}
static __device__ __forceinline__ float bfhi(unsigned int u) {
  union { unsigned int u; float f; } c; c.u = u & 0xffff0000u; return c.f;
}

// ---------------- degree histogram over edge dst ----------------
__global__ void k_hist(const int* __restrict__ dst, int* __restrict__ cnt, int e_total) {
  int e = blockIdx.x * blockDim.x + threadIdx.x;
  if (e < e_total) atomicAdd(&cnt[dst[e]], 1);
}

// ------- exclusive scan cnt -> rowptr; dinv = rsqrt(cnt+1) (self-loop) -------
__global__ __launch_bounds__(1024) void k_scan(const int* __restrict__ cnt,
                                               int* __restrict__ rowptr,
                                               float* __restrict__ dinv, int n) {
  const int tid = threadIdx.x;
  const int lane = tid & 63, wid = tid >> 6;
  __shared__ int wsum[16];
  int base = 0;
  const int PER = 8;
  const int CHUNK = 1024 * PER;
  for (int start = 0; start < n; start += CHUNK) {
    int idx0 = start + tid * PER;
    int v[PER]; int local = 0;
#pragma unroll
    for (int k = 0; k < PER; ++k) {
      int i = idx0 + k;
      v[k] = (i < n) ? cnt[i] : 0;
      local += v[k];
    }
    int sc = local;
#pragma unroll
    for (int off = 1; off < 64; off <<= 1) {
      int t = __shfl_up(sc, off, 64);
      if (lane >= off) sc += t;
    }
    if (lane == 63) wsum[wid] = sc;
    __syncthreads();
    if (wid == 0) {
      int ws_ = (lane < 16) ? wsum[lane] : 0;
#pragma unroll
      for (int off = 1; off < 16; off <<= 1) {
        int t = __shfl_up(ws_, off, 64);
        if (lane >= off) ws_ += t;
      }
      if (lane < 16) wsum[lane] = ws_;
    }
    __syncthreads();
    int wave_excl = (wid == 0) ? 0 : wsum[wid - 1];
    int excl = base + wave_excl + (sc - local);
#pragma unroll
    for (int k = 0; k < PER; ++k) {
      int i = idx0 + k;
      if (i < n) { rowptr[i] = excl; dinv[i] = rsqrtf((float)(v[k] + 1)); }
      excl += v[k];
    }
    int total = wsum[15];
    __syncthreads();
    base += total;
  }
  if (tid == 0) rowptr[n] = base;
}

// -------- CSR fill: edges bucketed by dst; packed (src, norm) --------
__global__ void k_fill(const int* __restrict__ src, const int* __restrict__ dst,
                       const int* __restrict__ rowptr, int* __restrict__ fillp,
                       int2* __restrict__ epk, const float* __restrict__ dinv,
                       int e_total) {
  int e = blockIdx.x * blockDim.x + threadIdx.x;
  if (e >= e_total) return;
  int s = src[e], d = dst[e];
  int p = rowptr[d] + atomicAdd(&fillp[d], 1);
  epk[p] = make_int2(s, __float_as_int(dinv[s] * dinv[d]));
}

// ---------------- W [K][C] fp32 -> Wt [C][K] bf16 ----------------
__global__ void k_transW(const float* __restrict__ W, unsigned short* __restrict__ Wt,
                         int K, int Ccols) {
  int idx = blockIdx.x * blockDim.x + threadIdx.x;
  if (idx >= K * Ccols) return;
  int nrow = idx / K, k = idx - nrow * K;
  Wt[idx] = f2bf(W[(size_t)k * Ccols + nrow]);
}

// ------- C[M][128] (bf16) = A[M][K] (fp32 or bf16) x Bt[128][K] (bf16) -------
// 128-row block, 256 thr = 4 waves; wave computes 2 row-tiles x 8 col-tiles (16x16x32)
template <int ABF>
__global__ __launch_bounds__(256) void k_gemm(const void* __restrict__ Av,
                                              const unsigned short* __restrict__ Bt,
                                              unsigned short* __restrict__ C,
                                              int M, int K) {
  __shared__ unsigned short As[128][40];  // +8 pad (16B) keeps ds_read_b128 clean
  __shared__ unsigned short Bs[128][40];
  const int tid = threadIdx.x;
  const int lane = tid & 63, wid = tid >> 6;
  const int row0 = blockIdx.x * 128;
  const int ar = tid >> 1;
  const int ah = (tid & 1) * 16;
  const int q = lane >> 4, r16 = lane & 15;

  f32x4 acc[2][8];
#pragma unroll
  for (int i = 0; i < 2; ++i)
#pragma unroll
    for (int j = 0; j < 8; ++j) { f32x4 z = {0.f, 0.f, 0.f, 0.f}; acc[i][j] = z; }

  const int grow = row0 + ar;
  const bool avalid = grow < M;
  const float* aprow = (const float*)Av + (size_t)grow * K + ah;
  const unsigned short* aprow16 = (const unsigned short*)Av + (size_t)grow * K + ah;
  const unsigned short* bprow = Bt + (size_t)ar * K + ah;

  for (int k0 = 0; k0 < K; k0 += 32) {
    if (ABF) {
#pragma unroll
      for (int i = 0; i < 2; ++i) {
        uint4 vv;
        if (avalid) vv = *(const uint4*)(aprow16 + k0 + i * 8);
        else { vv.x = 0; vv.y = 0; vv.z = 0; vv.w = 0; }
        *(uint4*)&As[ar][ah + i * 8] = vv;
      }
    } else {
#pragma unroll
      for (int i = 0; i < 4; ++i) {
        float4 v = avalid ? *(const float4*)(aprow + k0 + i * 4) : make_float4(0.f, 0.f, 0.f, 0.f);
        ushort4 b;
        b.x = f2bf(v.x); b.y = f2bf(v.y); b.z = f2bf(v.z); b.w = f2bf(v.w);
        *(ushort4*)&As[ar][ah + i * 4] = b;
      }
    }
#pragma unroll
    for (int i = 0; i < 2; ++i) {
      uint4 vv = *(const uint4*)(bprow + k0 + i * 8);
      *(uint4*)&Bs[ar][ah + i * 8] = vv;
    }
    __syncthreads();
    short8 afr[2], bfr[8];
#pragma unroll
    for (int i = 0; i < 2; ++i) {
      int rt = wid * 2 + i;
      afr[i] = *(const short8*)&As[rt * 16 + r16][q * 8];
    }
#pragma unroll
    for (int ct = 0; ct < 8; ++ct)
      bfr[ct] = *(const short8*)&Bs[ct * 16 + r16][q * 8];
#pragma unroll
    for (int i = 0; i < 2; ++i)
#pragma unroll
      for (int ct = 0; ct < 8; ++ct)
        acc[i][ct] = __builtin_amdgcn_mfma_f32_16x16x32_bf16(afr[i], bfr[ct], acc[i][ct], 0, 0, 0);
    __syncthreads();
  }

#pragma unroll
  for (int i = 0; i < 2; ++i) {
    int rt = wid * 2 + i;
#pragma unroll
    for (int rr = 0; rr < 4; ++rr) {
      int gr = row0 + rt * 16 + q * 4 + rr;
      if (gr < M) {
        unsigned short* cp = C + (size_t)gr * 128 + r16;
#pragma unroll
        for (int ct = 0; ct < 8; ++ct) cp[ct * 16] = f2bf(acc[i][ct][rr]);
      }
    }
  }
}

// ------- per-dst gather (CSR, bf16 h) + self-loop + bias + (ReLU) + BN -------
// one wave per dst row; lane owns channels 2*lane, 2*lane+1.
// Edge chunk loaded coalesced; inner loop manually unrolled x4 so FOUR
// independent h-row loads are in flight per wave (MLP=4, breaks the
// bpermute->load->fma serial chain that made the previous version
// latency-bound at ~1.4 TB/s effective).
__global__ __launch_bounds__(256) void k_gather(
    const unsigned short* __restrict__ h, const int* __restrict__ rowptr,
    const int2* __restrict__ epk, const float* __restrict__ dinv,
    const float* __restrict__ bias,
    const float* __restrict__ gg, const float* __restrict__ bb,
    const float* __restrict__ mm, const float* __restrict__ vv,
    unsigned short* __restrict__ out, int n, int relu) {
  int d = blockIdx.x * 4 + (threadIdx.x >> 6);
  if (d >= n) return;
  int lane = threadIdx.x & 63;
  const unsigned int* hp = (const unsigned int*)h;
  float wd = dinv[d];
  unsigned int hv = hp[(size_t)d * 64 + lane];
  float acx = wd * wd * bflo(hv), acy = wd * wd * bfhi(hv);
  float bcx = 0.f, bcy = 0.f;  // second accumulator pair (relax FMA chain)
  int j0 = rowptr[d], j1 = rowptr[d + 1];
  for (int base = j0; base < j1; base += 64) {
    int idx = base + lane;
    int2 e = epk[min(idx, j1 - 1)];
    int cntk = min(64, j1 - base);
    int k = 0;
    for (; k + 4 <= cntk; k += 4) {
      int s0 = __shfl(e.x, k, 64);
      int s1 = __shfl(e.x, k + 1, 64);
      int s2 = __shfl(e.x, k + 2, 64);
      int s3 = __shfl(e.x, k + 3, 64);
      float w0 = __int_as_float(__shfl(e.y, k, 64));
      float w1 = __int_as_float(__shfl(e.y, k + 1, 64));
      float w2 = __int_as_float(__shfl(e.y, k + 2, 64));
      float w3 = __int_as_float(__shfl(e.y, k + 3, 64));
      unsigned int x0 = hp[(size_t)s0 * 64 + lane];
      unsigned int x1 = hp[(size_t)s1 * 64 + lane];
      unsigned int x2 = hp[(size_t)s2 * 64 + lane];
      unsigned int x3 = hp[(size_t)s3 * 64 + lane];
      acx = fmaf(w0, bflo(x0), acx); acy = fmaf(w0, bfhi(x0), acy);
      bcx = fmaf(w1, bflo(x1), bcx); bcy = fmaf(w1, bfhi(x1), bcy);
      acx = fmaf(w2, bflo(x2), acx); acy = fmaf(w2, bfhi(x2), acy);
      bcx = fmaf(w3, bflo(x3), bcx); bcy = fmaf(w3, bfhi(x3), bcy);
    }
    for (; k < cntk; ++k) {
      int s = __shfl(e.x, k, 64);
      float w = __int_as_float(__shfl(e.y, k, 64));
      unsigned int x = hp[(size_t)s * 64 + lane];
      acx = fmaf(w, bflo(x), acx);
      acy = fmaf(w, bfhi(x), acy);
    }
  }
  acx += bcx; acy += bcy;
  float2 bia = ((const float2*)bias)[lane];
  float2 gv = ((const float2*)gg)[lane];
  float2 bv = ((const float2*)bb)[lane];
  float2 mv = ((const float2*)mm)[lane];
  float2 vva = ((const float2*)vv)[lane];
  float vx = acx + bia.x, vy = acy + bia.y;
  if (relu) { vx = fmaxf(vx, 0.f); vy = fmaxf(vy, 0.f); }
  float ox = (vx - mv.x) * (gv.x * rsqrtf(vva.x + 1e-5f)) + bv.x;
  float oy = (vy - mv.y) * (gv.y * rsqrtf(vva.y + 1e-5f)) + bv.y;
  unsigned int packed = (unsigned int)f2bf(ox) | ((unsigned int)f2bf(oy) << 16);
  ((unsigned int*)out)[(size_t)d * 64 + lane] = packed;
}

// ------------ mean-pool per graph (batch sorted -> binary search), bf16 in ------------
__global__ __launch_bounds__(256) void k_pool(const unsigned short* __restrict__ x,
                                              const int* __restrict__ batch,
                                              float* __restrict__ pooled, int n) {
  int b = blockIdx.x;
  int lo = 0, hi = n;
  while (lo < hi) { int mid = (lo + hi) >> 1; if (batch[mid] < b) lo = mid + 1; else hi = mid; }
  int start = lo;
  hi = n;
  while (lo < hi) { int mid = (lo + hi) >> 1; if (batch[mid] < b + 1) lo = mid + 1; else hi = mid; }
  int end = lo;
  int lane = threadIdx.x & 63, wid = threadIdx.x >> 6;
  const unsigned int* xp = (const unsigned int*)x;
  float ax = 0.f, ay = 0.f;
  for (int i = start + wid; i < end; i += 4) {
    unsigned int t = xp[(size_t)i * 64 + lane];
    ax += bflo(t); ay += bfhi(t);
  }
  __shared__ float px[4][64], py[4][64];
  px[wid][lane] = ax; py[wid][lane] = ay;
  __syncthreads();
  if (wid == 0) {
    float sx = px[0][lane] + px[1][lane] + px[2][lane] + px[3][lane];
    float sy = py[0][lane] + py[1][lane] + py[2][lane] + py[3][lane];
    float inv = 1.0f / fmaxf((float)(end - start), 1.0f);
    float2 o; o.x = sx * inv; o.y = sy * inv;
    ((float2*)pooled)[b * 64 + lane] = o;
  }
}

// ---------------- z = pooled + x_seq@fcW + fcb; two sigmoid heads ----------------
__global__ __launch_bounds__(256) void k_head(
    const float* __restrict__ pooled, const float* __restrict__ x_seq,
    const float* __restrict__ fcW, const float* __restrict__ fcb,
    const float* __restrict__ l0W, const float* __restrict__ l0b,
    const float* __restrict__ l1W, const float* __restrict__ l1b,
    float* __restrict__ out) {
  int b = blockIdx.x;
  int tid = threadIdx.x;
  __shared__ float xs[FIN];
  __shared__ float z[HH];
  for (int i = tid; i < FIN; i += 256) xs[i] = x_seq[(size_t)b * FIN + i];
  __syncthreads();
  if (tid < HH) {
    float acc = fcb[tid];
    for (int k = 0; k < FIN; ++k) acc = fmaf(xs[k], fcW[(size_t)k * HH + tid], acc);
    z[tid] = pooled[b * HH + tid] + acc;
  }
  __syncthreads();
  for (int o = tid; o < 365; o += 256) {
    if (o < 183) {
      float a = l0b[o];
      for (int k = 0; k < HH; ++k) a = fmaf(z[k], l0W[k * 183 + o], a);
      out[(size_t)b * 547 + o] = 1.f / (1.f + expf(-a));
    } else {
      int oo = o - 183;
      float a = l1b[oo];
      for (int k = 0; k < HH; ++k) a = fmaf(z[k], l1W[k * 182 + oo], a);
      float sv = 1.f / (1.f + expf(-a));
      out[(size_t)b * 547 + 183 + oo] = sv;
      out[(size_t)b * 547 + 365 + oo] = sv;
    }
  }
}

extern "C" void kernel_launch(void* const* d_in, const int* in_sizes, int n_in,
                              void* d_out, int out_size, void* d_ws, size_t ws_size,
                              hipStream_t stream) {
  const float* x_res = (const float*)d_in[0];
  const int*   eidx  = (const int*)d_in[1];
  const int*   batch = (const int*)d_in[2];
  const float* x_seq = (const float*)d_in[3];
  const float* W1 = (const float*)d_in[4];  const float* b1 = (const float*)d_in[5];
  const float* W2 = (const float*)d_in[6];  const float* b2 = (const float*)d_in[7];
  const float* W3 = (const float*)d_in[8];  const float* b3 = (const float*)d_in[9];
  const float* g1 = (const float*)d_in[10]; const float* be1 = (const float*)d_in[11];
  const float* m1 = (const float*)d_in[12]; const float* v1 = (const float*)d_in[13];
  const float* g2 = (const float*)d_in[14]; const float* be2 = (const float*)d_in[15];
  const float* m2 = (const float*)d_in[16]; const float* v2 = (const float*)d_in[17];
  const float* g3 = (const float*)d_in[18]; const float* be3 = (const float*)d_in[19];
  const float* m3 = (const float*)d_in[20]; const float* v3 = (const float*)d_in[21];
  const float* fcW = (const float*)d_in[22]; const float* fcb = (const float*)d_in[23];
  const float* l0W = (const float*)d_in[24]; const float* l0b = (const float*)d_in[25];
  const float* l1W = (const float*)d_in[26]; const float* l1b = (const float*)d_in[27];

  char* ws = (char*)d_ws;
  size_t off = 0;
  auto alloc = [&](size_t bytes) -> void* {
    void* p = ws + off;
    off += (bytes + 255) & ~(size_t)255;
    return p;
  };
  unsigned short* bufA = (unsigned short*)alloc((size_t)NN * HH * 2);
  unsigned short* bufB = (unsigned short*)alloc((size_t)NN * HH * 2);
  int* cnt    = (int*)alloc((size_t)NN * 4);
  int* rowptr = (int*)alloc(((size_t)NN + 1) * 4);
  int* fillp  = (int*)alloc((size_t)NN * 4);
  float* dinv = (float*)alloc((size_t)NN * 4);
  int2* epk   = (int2*)alloc((size_t)EE * 8);
  unsigned short* W1t = (unsigned short*)alloc((size_t)HH * FIN * 2);
  unsigned short* W2t = (unsigned short*)alloc((size_t)HH * HH * 2);
  unsigned short* W3t = (unsigned short*)alloc((size_t)HH * HH * 2);
  float* pooled = (float*)alloc((size_t)BBATCH * HH * 4);

  const int* esrc_in = eidx;
  const int* edst_in = eidx + EE;

  hipMemsetAsync(cnt, 0, (size_t)NN * 4, stream);
  hipMemsetAsync(fillp, 0, (size_t)NN * 4, stream);

  k_hist<<<(EE + 255) / 256, 256, 0, stream>>>(edst_in, cnt, EE);
  k_scan<<<1, 1024, 0, stream>>>(cnt, rowptr, dinv, NN);
  k_fill<<<(EE + 255) / 256, 256, 0, stream>>>(esrc_in, edst_in, rowptr, fillp, epk, dinv, EE);
  k_transW<<<(FIN * HH + 255) / 256, 256, 0, stream>>>(W1, W1t, FIN, HH);
  k_transW<<<(HH * HH + 255) / 256, 256, 0, stream>>>(W2, W2t, HH, HH);
  k_transW<<<(HH * HH + 255) / 256, 256, 0, stream>>>(W3, W3t, HH, HH);

  const int gemm_grid = (NN + 127) / 128;
  const int gat_grid  = (NN + 3) / 4;
  // layer 1 (A fp32)
  k_gemm<0><<<gemm_grid, 256, 0, stream>>>(x_res, W1t, bufA, NN, FIN);
  k_gather<<<gat_grid, 256, 0, stream>>>(bufA, rowptr, epk, dinv, b1, g1, be1, m1, v1, bufB, NN, 1);
  // layer 2 (A bf16)
  k_gemm<1><<<gemm_grid, 256, 0, stream>>>(bufB, W2t, bufA, NN, HH);
  k_gather<<<gat_grid, 256, 0, stream>>>(bufA, rowptr, epk, dinv, b2, g2, be2, m2, v2, bufB, NN, 1);
  // layer 3 (A bf16, no relu)
  k_gemm<1><<<gemm_grid, 256, 0, stream>>>(bufB, W3t, bufA, NN, HH);
  k_gather<<<gat_grid, 256, 0, stream>>>(bufA, rowptr, epk, dinv, b3, g3, be3, m3, v3, bufB, NN, 0);
  // pool + heads
  k_pool<<<BBATCH, 256, 0, stream>>>(bufB, batch, pooled, NN);
  k_head<<<BBATCH, 256, 0, stream>>>(pooled, x_seq, fcW, fcb, l0W, l0b, l1W, l1b, (float*)d_out);
}